// Round 1
// baseline (272.625 us; speedup 1.0000x reference)
//
#include <hip/hip_runtime.h>
#include <hip/hip_bf16.h>
#include <math.h>

typedef _Float16 f16x8 __attribute__((ext_vector_type(8)));
typedef float f32x4 __attribute__((ext_vector_type(4)));

#define LDH 264  // 256 + 8 f16 pad -> row stride 528B, 2-way bank aliasing (free)

// ---------------- A/B projection: A = xf @ W1[:258] + b1, B = xf @ W1[258:] ----
// grid 40 (= b*S), 512 threads. xf[p][c] = x[b,s,c,p] (c<256), coords at c=256,257.
__global__ void prep_ab(const float* __restrict__ x, const float* __restrict__ W1,
                        const float* __restrict__ b1,
                        float* __restrict__ A, float* __restrict__ B) {
    int bs = blockIdx.x;                       // (b*20+s)
    __shared__ float xs[258 * 16];             // [c][p]
    for (int i = threadIdx.x; i < 4096; i += 512) xs[i] = x[bs * 4096 + i];
    if (threadIdx.x < 32) {
        int p = threadIdx.x & 15;
        int c = 256 + (threadIdx.x >> 4);
        xs[c * 16 + p] = (float)((c == 256) ? (p >> 2) : (p & 3)) * 0.25f;
    }
    __syncthreads();
    int half = threadIdx.x >> 8;               // 0 -> A, 1 -> B
    int col  = threadIdx.x & 255;
    float acc[16];
#pragma unroll
    for (int p = 0; p < 16; p++) acc[p] = 0.f;
    const float* Wp = W1 + half * 258 * 256 + col;
    for (int c = 0; c < 258; c++) {
        float w = Wp[c * 256];
#pragma unroll
        for (int p = 0; p < 16; p++) acc[p] += xs[c * 16 + p] * w;
    }
    float* out = half ? B : A;
    float bias = half ? 0.f : b1[col];         // fold b1 into A once
#pragma unroll
    for (int p = 0; p < 16; p++) out[(bs * 16 + p) * 256 + col] = acc[p] + bias;
}

// ---------------- W2/W3/W4 -> f16, transposed to [N][K] for direct B-frag loads --
__global__ void prep_w(const float* __restrict__ W2, const float* __restrict__ W3,
                       const float* __restrict__ W4, _Float16* __restrict__ Wt) {
    int l = blockIdx.x >> 8, n = blockIdx.x & 255, k = threadIdx.x;
    const float* W = (l == 0) ? W2 : (l == 1) ? W3 : W4;
    Wt[l * 65536 + n * 256 + k] = (_Float16)W[k * 256 + n];
}

// ---------------- the big fused kernel ------------------------------------------
// grid 1600 = (b,s1,s2) x 2 row-halves; 512 threads = 8 waves (2x4 tile grid of 64x64)
__global__ __launch_bounds__(512, 2) void pairnet(
        const float* __restrict__ A, const float* __restrict__ B,
        const _Float16* __restrict__ Wt,
        const float* __restrict__ b2, const float* __restrict__ b3,
        const float* __restrict__ b4, float* __restrict__ pooled) {
    __shared__ _Float16 hbuf0[128 * LDH];
    __shared__ _Float16 hbuf1[128 * LDH];

    int blk  = blockIdx.x;
    int half = blk & 1;
    int s2   = (blk >> 1) % 20;
    int s1   = ((blk >> 1) / 20) % 20;
    int b    = blk / 800;
    int tid  = threadIdx.x;

    // layer 1: h1 = relu(A[b,s2,p2] + B[b,s1,p1])  (b1 pre-folded into A), fp32 -> f16
    const float* Abase = A + (b * 20 + s2) * 16 * 256;
    const float* Bbase = B + ((b * 20 + s1) * 16 + half * 8) * 256;
    for (int i = tid; i < 128 * 256; i += 512) {
        int r = i >> 8, c = i & 255;
        float v = Abase[(r & 15) * 256 + c] + Bbase[(r >> 4) * 256 + c];
        hbuf0[r * LDH + c] = (_Float16)fmaxf(v, 0.f);
    }
    __syncthreads();

    int wid = tid >> 6, lane = tid & 63;
    int row0 = (wid >> 2) * 64, col0 = (wid & 3) * 64;
    int lr = lane & 15, lk = lane >> 4;   // frag row/col index, k-group

    _Float16* bufs[2] = {hbuf0, hbuf1};
#pragma unroll
    for (int L = 0; L < 3; L++) {
        const _Float16* in  = bufs[L & 1];
        _Float16*       out = bufs[(L + 1) & 1];
        const _Float16* W   = Wt + L * 65536;
        const float*  bias  = (L == 0) ? b2 : (L == 1) ? b3 : b4;

        f32x4 acc[4][4];
#pragma unroll
        for (int m = 0; m < 4; m++)
#pragma unroll
            for (int n = 0; n < 4; n++) acc[m][n] = (f32x4){0.f, 0.f, 0.f, 0.f};

        for (int k0 = 0; k0 < 256; k0 += 32) {
            f16x8 a[4], w[4];
#pragma unroll
            for (int m = 0; m < 4; m++)
                a[m] = *(const f16x8*)(in + (row0 + 16 * m + lr) * LDH + k0 + 8 * lk);
#pragma unroll
            for (int n = 0; n < 4; n++)
                w[n] = *(const f16x8*)(W + (col0 + 16 * n + lr) * 256 + k0 + 8 * lk);
#pragma unroll
            for (int m = 0; m < 4; m++)
#pragma unroll
                for (int n = 0; n < 4; n++)
                    acc[m][n] = __builtin_amdgcn_mfma_f32_16x16x32_f16(a[m], w[n], acc[m][n], 0, 0, 0);
        }

        if (L < 2) {
#pragma unroll
            for (int n = 0; n < 4; n++) {
                int col = col0 + 16 * n + lr;
                float bs = bias[col];
#pragma unroll
                for (int m = 0; m < 4; m++)
#pragma unroll
                    for (int j = 0; j < 4; j++) {
                        int row = row0 + 16 * m + 4 * lk + j;
                        out[row * LDH + col] = (_Float16)fmaxf(acc[m][n][j] + bs, 0.f);
                    }
            }
            __syncthreads();
        } else {
            // layer 4: bias+relu then pool over this wave's 64 rows, atomicAdd
#pragma unroll
            for (int n = 0; n < 4; n++) {
                int col = col0 + 16 * n + lr;
                float bs = bias[col];
                float s = 0.f;
#pragma unroll
                for (int m = 0; m < 4; m++)
#pragma unroll
                    for (int j = 0; j < 4; j++)
                        s += fmaxf(acc[m][n][j] + bs, 0.f);
                s += __shfl_xor(s, 16);
                s += __shfl_xor(s, 32);
                if (lane < 16)
                    atomicAdd(&pooled[((b * 20 + s1) * 20 + s2) * 256 + col], s);
            }
        }
    }
}

// ---------------- final MLP on pooled [800,256] ---------------------------------
__global__ void final_mlp(const float* __restrict__ pooled,
        const float* __restrict__ Wf1, const float* __restrict__ bf1,
        const float* __restrict__ Wf2, const float* __restrict__ bf2,
        const float* __restrict__ Wf3, const float* __restrict__ bf3,
        const float* __restrict__ Wf4, const float* __restrict__ bf4,
        float* __restrict__ out) {
    __shared__ float p[4][256], y[4][256], z[4][256], y3[4][29];
    int r0 = blockIdx.x * 4;
    int t  = threadIdx.x;
    for (int i = t; i < 1024; i += 256) p[i >> 8][i & 255] = pooled[r0 * 256 + i];
    __syncthreads();
    float acc[4];
#pragma unroll
    for (int r = 0; r < 4; r++) acc[r] = bf1[t];
    for (int k = 0; k < 256; k++) {
        float w = Wf1[k * 256 + t];
#pragma unroll
        for (int r = 0; r < 4; r++) acc[r] += p[r][k] * w;
    }
#pragma unroll
    for (int r = 0; r < 4; r++) y[r][t] = fmaxf(acc[r], 0.f);
    __syncthreads();
#pragma unroll
    for (int r = 0; r < 4; r++) acc[r] = bf2[t];
    for (int k = 0; k < 256; k++) {
        float w = Wf2[k * 256 + t];
#pragma unroll
        for (int r = 0; r < 4; r++) acc[r] += y[r][k] * w;
    }
#pragma unroll
    for (int r = 0; r < 4; r++) z[r][t] = fmaxf(acc[r], 0.f);
    __syncthreads();
    if (t < 116) {
        int r = t / 29, c = t % 29;
        float a = bf3[c];
        for (int k = 0; k < 256; k++) a += z[r][k] * Wf3[k * 29 + c];
        y3[r][c] = fmaxf(a, 0.f);
    }
    __syncthreads();
    if (t < 4) {
        float zz = bf4[0];
#pragma unroll
        for (int c = 0; c < 29; c++) zz += y3[t][c] * Wf4[c];
        out[r0 + t] = 1.f / (1.f + expf(-zz));
    }
}

extern "C" void kernel_launch(void* const* d_in, const int* in_sizes, int n_in,
                              void* d_out, int out_size, void* d_ws, size_t ws_size,
                              hipStream_t stream) {
    const float* x   = (const float*)d_in[0];
    const float* W1  = (const float*)d_in[1];
    const float* b1  = (const float*)d_in[2];
    const float* W2  = (const float*)d_in[3];
    const float* b2  = (const float*)d_in[4];
    const float* W3  = (const float*)d_in[5];
    const float* b3  = (const float*)d_in[6];
    const float* W4  = (const float*)d_in[7];
    const float* b4  = (const float*)d_in[8];
    const float* Wf1 = (const float*)d_in[9];
    const float* bf1 = (const float*)d_in[10];
    const float* Wf2 = (const float*)d_in[11];
    const float* bf2 = (const float*)d_in[12];
    const float* Wf3 = (const float*)d_in[13];
    const float* bf3 = (const float*)d_in[14];
    const float* Wf4 = (const float*)d_in[15];
    const float* bf4 = (const float*)d_in[16];

    float* A      = (float*)d_ws;                 // 640*256 f32
    float* B      = A + 640 * 256;                // 640*256 f32
    float* pooled = B + 640 * 256;                // 800*256 f32
    _Float16* Wt  = (_Float16*)(pooled + 800 * 256); // 3*256*256 f16

    hipMemsetAsync(pooled, 0, 800 * 256 * sizeof(float), stream);
    prep_ab<<<40, 512, 0, stream>>>(x, W1, b1, A, B);
    prep_w<<<768, 256, 0, stream>>>(W2, W3, W4, Wt);
    pairnet<<<1600, 512, 0, stream>>>(A, B, Wt, b2, b3, b4, pooled);
    final_mlp<<<200, 256, 0, stream>>>(pooled, Wf1, bf1, Wf2, bf2, Wf3, bf3, Wf4, bf4,
                                       (float*)d_out);
}

// Round 2
// 228.767 us; speedup vs baseline: 1.1917x; 1.1917x over previous
//
#include <hip/hip_runtime.h>
#include <hip/hip_bf16.h>
#include <math.h>

typedef _Float16 f16x8 __attribute__((ext_vector_type(8)));
typedef _Float16 f16x4 __attribute__((ext_vector_type(4)));
typedef float f32x4 __attribute__((ext_vector_type(4)));

#define LDH 264  // 256 + 8 f16 pad (528B row stride)
// XOR swizzle (element units): flips 32B bit by row bit 2 -> breaks 4-way aliasing
#define SWZ(r, idx) ((idx) ^ (((r) & 4) << 2))

// ---------------- A/B projection: A = xf @ W1[:258] + b1, B = xf @ W1[258:] ----
// grid 160 = (b*S) x 4 p-groups, 512 threads.
__global__ void prep_ab(const float* __restrict__ x, const float* __restrict__ W1,
                        const float* __restrict__ b1,
                        float* __restrict__ A, float* __restrict__ B) {
    int blk = blockIdx.x;
    int bs = blk >> 2, pg = blk & 3;           // 4 p-values per block
    __shared__ float xs[258 * 4];              // [c][pp]
    for (int i = threadIdx.x; i < 1024; i += 512) {
        int c = i >> 2, pp = i & 3;
        xs[i] = x[bs * 4096 + c * 16 + pg * 4 + pp];
    }
    if (threadIdx.x < 8) {
        int pp = threadIdx.x & 3, c = 256 + (threadIdx.x >> 2);
        int p = pg * 4 + pp;
        xs[c * 4 + pp] = (float)((c == 256) ? (p >> 2) : (p & 3)) * 0.25f;
    }
    __syncthreads();
    int half = threadIdx.x >> 8;               // 0 -> A, 1 -> B
    int col  = threadIdx.x & 255;
    float acc[4] = {0.f, 0.f, 0.f, 0.f};
    const float* Wp = W1 + half * 258 * 256 + col;
    for (int c = 0; c < 258; c++) {
        float w = Wp[c * 256];
#pragma unroll
        for (int pp = 0; pp < 4; pp++) acc[pp] += xs[c * 4 + pp] * w;
    }
    float* out = half ? B : A;
    float bias = half ? 0.f : b1[col];         // fold b1 into A once
#pragma unroll
    for (int pp = 0; pp < 4; pp++)
        out[(bs * 16 + pg * 4 + pp) * 256 + col] = acc[pp] + bias;
}

// ---------------- W2/W3/W4 -> f16, transposed to [N][K] for direct B-frag loads --
__global__ void prep_w(const float* __restrict__ W2, const float* __restrict__ W3,
                       const float* __restrict__ W4, _Float16* __restrict__ Wt) {
    int l = blockIdx.x >> 8, n = blockIdx.x & 255, k = threadIdx.x;
    const float* W = (l == 0) ? W2 : (l == 1) ? W3 : W4;
    Wt[l * 65536 + n * 256 + k] = (_Float16)W[k * 256 + n];
}

// ---------------- the big fused kernel ------------------------------------------
// grid 3200 = (b,s1,s2) x 4 row-quarters; 256 threads = 4 waves, each 64rows x 64cols
__global__ __launch_bounds__(256, 2) void pairnet(
        const float* __restrict__ A, const float* __restrict__ B,
        const _Float16* __restrict__ Wt,
        const float* __restrict__ b2, const float* __restrict__ b3,
        const float* __restrict__ b4, float* __restrict__ pooled) {
    __shared__ _Float16 hb0[64 * LDH];   // 33.8 KB
    __shared__ _Float16 hb1[64 * LDH];   // total 67.6 KB -> 2 blocks/CU

    int blk = blockIdx.x;
    int qtr = blk & 3;
    int s2  = (blk >> 2) % 20;
    int s1  = ((blk >> 2) / 20) % 20;
    int b   = blk / 1600;
    int tid = threadIdx.x;

    // ---- layer 1: h1 = relu(A[b,s2,p2] + B[b,s1,p1]), fp32 -> f16 into hb0 ----
    const float* Abase = A + (b * 20 + s2) * 16 * 256;
    const float* Bbase = B + ((b * 20 + s1) * 16 + qtr * 4) * 256;
#pragma unroll
    for (int it = 0; it < 16; it++) {
        int u = it * 256 + tid;            // 0..4095 float4-units
        int r = u >> 6;                    // row 0..63
        int c = (u & 63) * 4;              // col
        float4 av = *(const float4*)(Abase + (r & 15) * 256 + c);
        float4 bv = *(const float4*)(Bbase + (r >> 4) * 256 + c);
        f16x4 hv;
        hv[0] = (_Float16)fmaxf(av.x + bv.x, 0.f);
        hv[1] = (_Float16)fmaxf(av.y + bv.y, 0.f);
        hv[2] = (_Float16)fmaxf(av.z + bv.z, 0.f);
        hv[3] = (_Float16)fmaxf(av.w + bv.w, 0.f);
        *(f16x4*)(hb0 + SWZ(r, r * LDH + c)) = hv;
    }
    __syncthreads();

    int wid = tid >> 6, lane = tid & 63;
    int col0 = wid * 64;                   // wave owns 64 cols x all 64 rows
    int lr = lane & 15, lk = lane >> 4;    // frag row/col, k-quarter
    int aswz = (lr & 4) << 2;              // row&4 == lr&4 for rows 16m+lr

#pragma unroll
    for (int L = 0; L < 3; L++) {
        const _Float16* in  = (L & 1) ? hb1 : hb0;
        _Float16*       out = (L & 1) ? hb0 : hb1;
        const _Float16* W   = Wt + L * 65536;
        const float* bias   = (L == 0) ? b2 : (L == 1) ? b3 : b4;

        f32x4 acc[4][4];
#pragma unroll
        for (int m = 0; m < 4; m++)
#pragma unroll
            for (int n = 0; n < 4; n++) acc[m][n] = (f32x4){0.f, 0.f, 0.f, 0.f};

#pragma unroll
        for (int kh = 0; kh < 2; kh++) {
            // preload this k-half's W frags (16 loads, 64 VGPRs) from L2
            f16x8 w[4][4];
#pragma unroll
            for (int kk = 0; kk < 4; kk++)
#pragma unroll
                for (int n = 0; n < 4; n++)
                    w[kk][n] = *(const f16x8*)(W + (col0 + 16 * n + lr) * 256 +
                                               kh * 128 + kk * 32 + 8 * lk);
#pragma unroll
            for (int kk = 0; kk < 4; kk++) {
                int koff = kh * 128 + kk * 32 + 8 * lk;
                f16x8 a[4];
#pragma unroll
                for (int m = 0; m < 4; m++)
                    a[m] = *(const f16x8*)(in + (((16 * m + lr) * LDH + koff) ^ aswz));
#pragma unroll
                for (int m = 0; m < 4; m++)
#pragma unroll
                    for (int n = 0; n < 4; n++)
                        acc[m][n] = __builtin_amdgcn_mfma_f32_16x16x32_f16(
                            a[m], w[kk][n], acc[m][n], 0, 0, 0);
            }
        }

        if (L < 2) {
#pragma unroll
            for (int n = 0; n < 4; n++) {
                int col = col0 + 16 * n + lr;
                float bs = bias[col];
#pragma unroll
                for (int m = 0; m < 4; m++)
#pragma unroll
                    for (int j = 0; j < 4; j++) {
                        int row = 16 * m + 4 * lk + j;
                        out[SWZ(row, row * LDH + col)] =
                            (_Float16)fmaxf(acc[m][n][j] + bs, 0.f);
                    }
            }
            __syncthreads();
        } else {
            // layer 4: bias+relu, pool all 64 rows (rows partitioned over m,lk,j)
#pragma unroll
            for (int n = 0; n < 4; n++) {
                int col = col0 + 16 * n + lr;
                float bs = bias[col];
                float s = 0.f;
#pragma unroll
                for (int m = 0; m < 4; m++)
#pragma unroll
                    for (int j = 0; j < 4; j++)
                        s += fmaxf(acc[m][n][j] + bs, 0.f);
                s += __shfl_xor(s, 16);
                s += __shfl_xor(s, 32);
                if (lane < 16)
                    atomicAdd(&pooled[((b * 20 + s1) * 20 + s2) * 256 + col], s);
            }
        }
    }
}

// ---------------- final MLP on pooled [800,256] ---------------------------------
__global__ void final_mlp(const float* __restrict__ pooled,
        const float* __restrict__ Wf1, const float* __restrict__ bf1,
        const float* __restrict__ Wf2, const float* __restrict__ bf2,
        const float* __restrict__ Wf3, const float* __restrict__ bf3,
        const float* __restrict__ Wf4, const float* __restrict__ bf4,
        float* __restrict__ out) {
    __shared__ float p[4][256], y[4][256], z[4][256], y3[4][29];
    int r0 = blockIdx.x * 4;
    int t  = threadIdx.x;
    for (int i = t; i < 1024; i += 256) p[i >> 8][i & 255] = pooled[r0 * 256 + i];
    __syncthreads();
    float acc[4];
#pragma unroll
    for (int r = 0; r < 4; r++) acc[r] = bf1[t];
    for (int k = 0; k < 256; k++) {
        float w = Wf1[k * 256 + t];
#pragma unroll
        for (int r = 0; r < 4; r++) acc[r] += p[r][k] * w;
    }
#pragma unroll
    for (int r = 0; r < 4; r++) y[r][t] = fmaxf(acc[r], 0.f);
    __syncthreads();
#pragma unroll
    for (int r = 0; r < 4; r++) acc[r] = bf2[t];
    for (int k = 0; k < 256; k++) {
        float w = Wf2[k * 256 + t];
#pragma unroll
        for (int r = 0; r < 4; r++) acc[r] += y[r][k] * w;
    }
#pragma unroll
    for (int r = 0; r < 4; r++) z[r][t] = fmaxf(acc[r], 0.f);
    __syncthreads();
    if (t < 116) {
        int r = t / 29, c = t % 29;
        float a = bf3[c];
        for (int k = 0; k < 256; k++) a += z[r][k] * Wf3[k * 29 + c];
        y3[r][c] = fmaxf(a, 0.f);
    }
    __syncthreads();
    if (t < 4) {
        float zz = bf4[0];
#pragma unroll
        for (int c = 0; c < 29; c++) zz += y3[t][c] * Wf4[c];
        out[r0 + t] = 1.f / (1.f + expf(-zz));
    }
}

extern "C" void kernel_launch(void* const* d_in, const int* in_sizes, int n_in,
                              void* d_out, int out_size, void* d_ws, size_t ws_size,
                              hipStream_t stream) {
    const float* x   = (const float*)d_in[0];
    const float* W1  = (const float*)d_in[1];
    const float* b1  = (const float*)d_in[2];
    const float* W2  = (const float*)d_in[3];
    const float* b2  = (const float*)d_in[4];
    const float* W3  = (const float*)d_in[5];
    const float* b3  = (const float*)d_in[6];
    const float* W4  = (const float*)d_in[7];
    const float* b4  = (const float*)d_in[8];
    const float* Wf1 = (const float*)d_in[9];
    const float* bf1 = (const float*)d_in[10];
    const float* Wf2 = (const float*)d_in[11];
    const float* bf2 = (const float*)d_in[12];
    const float* Wf3 = (const float*)d_in[13];
    const float* bf3 = (const float*)d_in[14];
    const float* Wf4 = (const float*)d_in[15];
    const float* bf4 = (const float*)d_in[16];

    float* A      = (float*)d_ws;                    // 640*256 f32
    float* B      = A + 640 * 256;                   // 640*256 f32
    float* pooled = B + 640 * 256;                   // 800*256 f32
    _Float16* Wt  = (_Float16*)(pooled + 800 * 256); // 3*256*256 f16

    hipMemsetAsync(pooled, 0, 800 * 256 * sizeof(float), stream);
    prep_ab<<<160, 512, 0, stream>>>(x, W1, b1, A, B);
    prep_w<<<768, 256, 0, stream>>>(W2, W3, W4, Wt);
    pairnet<<<3200, 256, 0, stream>>>(A, B, Wt, b2, b3, b4, pooled);
    final_mlp<<<200, 256, 0, stream>>>(pooled, Wf1, bf1, Wf2, bf2, Wf3, bf3, Wf4, bf4,
                                       (float*)d_out);
}

// Round 3
// 185.006 us; speedup vs baseline: 1.4736x; 1.2365x over previous
//
#include <hip/hip_runtime.h>
#include <hip/hip_bf16.h>
#include <math.h>

typedef _Float16 f16x8 __attribute__((ext_vector_type(8)));
typedef _Float16 f16x4 __attribute__((ext_vector_type(4)));
typedef float f32x4 __attribute__((ext_vector_type(4)));

#define LDH 264  // 256 + 8 f16 pad (528B row stride)
#define SWZ(r, idx) ((idx) ^ (((r) & 4) << 2))

// ---------------- A/B projection: A = xf @ W1[:258] + b1, B = xf @ W1[258:] ----
__global__ void prep_ab(const float* __restrict__ x, const float* __restrict__ W1,
                        const float* __restrict__ b1,
                        float* __restrict__ A, float* __restrict__ B) {
    int blk = blockIdx.x;
    int bs = blk >> 2, pg = blk & 3;           // 4 p-values per block
    __shared__ float xs[258 * 4];              // [c][pp]
    for (int i = threadIdx.x; i < 1024; i += 512) {
        int c = i >> 2, pp = i & 3;
        xs[i] = x[bs * 4096 + c * 16 + pg * 4 + pp];
    }
    if (threadIdx.x < 8) {
        int pp = threadIdx.x & 3, c = 256 + (threadIdx.x >> 2);
        int p = pg * 4 + pp;
        xs[c * 4 + pp] = (float)((c == 256) ? (p >> 2) : (p & 3)) * 0.25f;
    }
    __syncthreads();
    int half = threadIdx.x >> 8;               // 0 -> A, 1 -> B
    int col  = threadIdx.x & 255;
    float acc[4] = {0.f, 0.f, 0.f, 0.f};
    const float* Wp = W1 + half * 258 * 256 + col;
    for (int c = 0; c < 258; c++) {
        float w = Wp[c * 256];
#pragma unroll
        for (int pp = 0; pp < 4; pp++) acc[pp] += xs[c * 4 + pp] * w;
    }
    float* out = half ? B : A;
    float bias = half ? 0.f : b1[col];         // fold b1 into A once
#pragma unroll
    for (int pp = 0; pp < 4; pp++)
        out[(bs * 16 + pg * 4 + pp) * 256 + col] = acc[pp] + bias;
}

// ---- W2/W3/W4 -> f16 fragment-contiguous layout: flat = frag*512 + lane*8 + e --
// frag = (L*16 + cg)*8 + kk ; col = cg*16 + (lane&15) ; k = kk*32 + (lane>>4)*8 + e
__global__ void prep_w(const float* __restrict__ W2, const float* __restrict__ W3,
                       const float* __restrict__ W4, _Float16* __restrict__ Wt) {
    int blk = blockIdx.x;                      // = frag index, 0..383
    int t   = threadIdx.x;                     // 0..511 = lane*8 + e
    int kk = blk & 7, cg = (blk >> 3) & 15, L = blk >> 7;
    int l = t >> 3, e = t & 7;
    int col = cg * 16 + (l & 15);
    int k   = kk * 32 + (l >> 4) * 8 + e;
    const float* W = (L == 0) ? W2 : (L == 1) ? W3 : W4;
    Wt[blk * 512 + t] = (_Float16)W[k * 256 + col];
}

// ---------------- the big fused kernel ------------------------------------------
// grid 3200 = (b,s1,s2) x 4 row-quarters; 256 threads = 4 waves x (64r x 64c)
// single in-place LDS h buffer (33.8KB) -> 4 blocks/CU target
__global__ __launch_bounds__(256, 4) void pairnet(
        const float* __restrict__ A, const float* __restrict__ B,
        const _Float16* __restrict__ Wt,
        const float* __restrict__ b2, const float* __restrict__ b3,
        const float* __restrict__ b4, float* __restrict__ pooled4) {
    __shared__ _Float16 hb[64 * LDH];          // 33.8 KB

    int blk = blockIdx.x;
    int qtr = blk & 3;
    int bss = blk >> 2;                        // (b*20+s1)*20+s2
    int s2  = bss % 20;
    int s1  = (bss / 20) % 20;
    int b   = bss / 400;
    int tid = threadIdx.x;

    // ---- layer 1: h1 = relu(A[b,s2,p2] + B[b,s1,p1]), fp32 -> f16 into hb ----
    const float* Abase = A + (b * 20 + s2) * 16 * 256;
    const float* Bbase = B + ((b * 20 + s1) * 16 + qtr * 4) * 256;
#pragma unroll
    for (int it = 0; it < 16; it++) {
        int u = it * 256 + tid;            // float4-units
        int r = u >> 6;                    // row 0..63 (= p1loc*16 + p2)
        int c = (u & 63) * 4;              // col
        float4 av = *(const float4*)(Abase + (r & 15) * 256 + c);
        float4 bv = *(const float4*)(Bbase + (r >> 4) * 256 + c);
        f16x4 hv;
        hv[0] = (_Float16)fmaxf(av.x + bv.x, 0.f);
        hv[1] = (_Float16)fmaxf(av.y + bv.y, 0.f);
        hv[2] = (_Float16)fmaxf(av.z + bv.z, 0.f);
        hv[3] = (_Float16)fmaxf(av.w + bv.w, 0.f);
        *(f16x4*)(hb + SWZ(r, r * LDH + c)) = hv;
    }
    __syncthreads();

    int wid = tid >> 6, lane = tid & 63;
    int col0 = wid * 64;                   // wave owns 64 cols x all 64 rows
    int lr = lane & 15, lk = lane >> 4;
    int aswz = (lr & 4) << 2;              // row&4 == lr&4 for rows 16m+lr

#pragma unroll
    for (int L = 0; L < 3; L++) {
        const float* bias = (L == 0) ? b2 : (L == 1) ? b3 : b4;
        // fragment-contiguous W base for this wave's 4 col-groups
        const _Float16* wb = Wt + (size_t)((L * 16 + wid * 4) * 8) * 512 + lane * 8;

        f32x4 acc[4][4];
#pragma unroll
        for (int m = 0; m < 4; m++)
#pragma unroll
            for (int n = 0; n < 4; n++) acc[m][n] = (f32x4){0.f, 0.f, 0.f, 0.f};

#pragma unroll
        for (int kk = 0; kk < 8; kk++) {
            f16x8 w[4], a[4];
#pragma unroll
            for (int n = 0; n < 4; n++)
                w[n] = *(const f16x8*)(wb + (n * 8 + kk) * 512);
#pragma unroll
            for (int m = 0; m < 4; m++)
                a[m] = *(const f16x8*)(hb + (((16 * m + lr) * LDH + kk * 32 + 8 * lk) ^ aswz));
            // swapped operands -> transposed D: thread holds rows 16m+lr,
            // cols col0+16n+4lk+{0..3}
#pragma unroll
            for (int m = 0; m < 4; m++)
#pragma unroll
                for (int n = 0; n < 4; n++)
                    acc[m][n] = __builtin_amdgcn_mfma_f32_16x16x32_f16(
                        w[n], a[m], acc[m][n], 0, 0, 0);
        }

        if (L < 2) {
            __syncthreads();               // all reads of hb complete
#pragma unroll
            for (int n = 0; n < 4; n++) {
                int cb = col0 + 16 * n + 4 * lk;
                float4 b4v = *(const float4*)(bias + cb);
#pragma unroll
                for (int m = 0; m < 4; m++) {
                    int row = 16 * m + lr;
                    f16x4 hv;
                    hv[0] = (_Float16)fmaxf(acc[m][n][0] + b4v.x, 0.f);
                    hv[1] = (_Float16)fmaxf(acc[m][n][1] + b4v.y, 0.f);
                    hv[2] = (_Float16)fmaxf(acc[m][n][2] + b4v.z, 0.f);
                    hv[3] = (_Float16)fmaxf(acc[m][n][3] + b4v.w, 0.f);
                    *(f16x4*)(hb + SWZ(row, row * LDH + cb)) = hv;
                }
            }
            __syncthreads();               // writes visible
        } else {
            // layer 4: bias+relu, pool over 64 rows (m in-thread, lr butterfly)
#pragma unroll
            for (int n = 0; n < 4; n++) {
                int cb = col0 + 16 * n + 4 * lk;
                float4 b4v = *(const float4*)(bias + cb);
                f32x4 s = (f32x4){0.f, 0.f, 0.f, 0.f};
#pragma unroll
                for (int m = 0; m < 4; m++) {
                    s[0] += fmaxf(acc[m][n][0] + b4v.x, 0.f);
                    s[1] += fmaxf(acc[m][n][1] + b4v.y, 0.f);
                    s[2] += fmaxf(acc[m][n][2] + b4v.z, 0.f);
                    s[3] += fmaxf(acc[m][n][3] + b4v.w, 0.f);
                }
#pragma unroll
                for (int mask = 1; mask <= 8; mask <<= 1) {
#pragma unroll
                    for (int c = 0; c < 4; c++) s[c] += __shfl_xor(s[c], mask);
                }
                if (lr == 0) {
                    float4 sv; sv.x = s[0]; sv.y = s[1]; sv.z = s[2]; sv.w = s[3];
                    *(float4*)(pooled4 + ((size_t)qtr * 800 + bss) * 256 + cb) = sv;
                }
            }
        }
    }
}

// ---------------- final MLP on pooled [800,256] (sums 4 qtr slabs) --------------
__global__ void final_mlp(const float* __restrict__ pooled4,
        const float* __restrict__ Wf1, const float* __restrict__ bf1,
        const float* __restrict__ Wf2, const float* __restrict__ bf2,
        const float* __restrict__ Wf3, const float* __restrict__ bf3,
        const float* __restrict__ Wf4, const float* __restrict__ bf4,
        float* __restrict__ out) {
    __shared__ float p[4][256], y[4][256], z[4][256], y3[4][29];
    int r0 = blockIdx.x * 4;
    int t  = threadIdx.x;
    for (int i = t; i < 1024; i += 256) {
        int r = i >> 8, c = i & 255;
        float v = 0.f;
#pragma unroll
        for (int q = 0; q < 4; q++)
            v += pooled4[((size_t)q * 800 + r0 + r) * 256 + c];
        p[r][c] = v;
    }
    __syncthreads();
    float acc[4];
#pragma unroll
    for (int r = 0; r < 4; r++) acc[r] = bf1[t];
    for (int k = 0; k < 256; k++) {
        float w = Wf1[k * 256 + t];
#pragma unroll
        for (int r = 0; r < 4; r++) acc[r] += p[r][k] * w;
    }
#pragma unroll
    for (int r = 0; r < 4; r++) y[r][t] = fmaxf(acc[r], 0.f);
    __syncthreads();
#pragma unroll
    for (int r = 0; r < 4; r++) acc[r] = bf2[t];
    for (int k = 0; k < 256; k++) {
        float w = Wf2[k * 256 + t];
#pragma unroll
        for (int r = 0; r < 4; r++) acc[r] += y[r][k] * w;
    }
#pragma unroll
    for (int r = 0; r < 4; r++) z[r][t] = fmaxf(acc[r], 0.f);
    __syncthreads();
    if (t < 116) {
        int r = t / 29, c = t % 29;
        float a = bf3[c];
        for (int k = 0; k < 256; k++) a += z[r][k] * Wf3[k * 29 + c];
        y3[r][c] = fmaxf(a, 0.f);
    }
    __syncthreads();
    if (t < 4) {
        float zz = bf4[0];
#pragma unroll
        for (int c = 0; c < 29; c++) zz += y3[t][c] * Wf4[c];
        out[r0 + t] = 1.f / (1.f + expf(-zz));
    }
}

extern "C" void kernel_launch(void* const* d_in, const int* in_sizes, int n_in,
                              void* d_out, int out_size, void* d_ws, size_t ws_size,
                              hipStream_t stream) {
    const float* x   = (const float*)d_in[0];
    const float* W1  = (const float*)d_in[1];
    const float* b1  = (const float*)d_in[2];
    const float* W2  = (const float*)d_in[3];
    const float* b2  = (const float*)d_in[4];
    const float* W3  = (const float*)d_in[5];
    const float* b3  = (const float*)d_in[6];
    const float* W4  = (const float*)d_in[7];
    const float* b4  = (const float*)d_in[8];
    const float* Wf1 = (const float*)d_in[9];
    const float* bf1 = (const float*)d_in[10];
    const float* Wf2 = (const float*)d_in[11];
    const float* bf2 = (const float*)d_in[12];
    const float* Wf3 = (const float*)d_in[13];
    const float* bf3 = (const float*)d_in[14];
    const float* Wf4 = (const float*)d_in[15];
    const float* bf4 = (const float*)d_in[16];

    float* A       = (float*)d_ws;                     // 640*256 f32
    float* B       = A + 640 * 256;                    // 640*256 f32
    float* pooled4 = B + 640 * 256;                    // 4*800*256 f32
    _Float16* Wt   = (_Float16*)(pooled4 + 4 * 800 * 256); // 384 frags * 512 f16

    prep_ab<<<160, 512, 0, stream>>>(x, W1, b1, A, B);
    prep_w<<<384, 512, 0, stream>>>(W2, W3, W4, Wt);
    pairnet<<<3200, 256, 0, stream>>>(A, B, Wt, b2, b3, b4, pooled4);
    final_mlp<<<200, 256, 0, stream>>>(pooled4, Wf1, bf1, Wf2, bf2, Wf3, bf3, Wf4, bf4,
                                       (float*)d_out);
}

// Round 4
// 121.749 us; speedup vs baseline: 2.2392x; 1.5196x over previous
//
#include <hip/hip_runtime.h>
#include <hip/hip_bf16.h>
#include <math.h>

typedef _Float16 f16x8 __attribute__((ext_vector_type(8)));
typedef _Float16 f16x4 __attribute__((ext_vector_type(4)));
typedef float f32x4 __attribute__((ext_vector_type(4)));

#define LDH 264  // 256 + 8 f16 pad -> row stride 132 dwords: 4-bank rotation/row,
                 // b128 reads & b64 writes are bank-balanced with NO swizzle

// ---------------- A/B projection: A = xf @ W1[:258] + b1, B = xf @ W1[258:] ----
__global__ void prep_ab(const float* __restrict__ x, const float* __restrict__ W1,
                        const float* __restrict__ b1,
                        float* __restrict__ A, float* __restrict__ B) {
    int blk = blockIdx.x;
    int bs = blk >> 2, pg = blk & 3;           // 4 p-values per block
    __shared__ float xs[258 * 4];              // [c][pp]
    for (int i = threadIdx.x; i < 1024; i += 512) {
        int c = i >> 2, pp = i & 3;
        xs[i] = x[bs * 4096 + c * 16 + pg * 4 + pp];
    }
    if (threadIdx.x < 8) {
        int pp = threadIdx.x & 3, c = 256 + (threadIdx.x >> 2);
        int p = pg * 4 + pp;
        xs[c * 4 + pp] = (float)((c == 256) ? (p >> 2) : (p & 3)) * 0.25f;
    }
    __syncthreads();
    int half = threadIdx.x >> 8;               // 0 -> A, 1 -> B
    int col  = threadIdx.x & 255;
    float acc[4] = {0.f, 0.f, 0.f, 0.f};
    const float* Wp = W1 + half * 258 * 256 + col;
    for (int c = 0; c < 258; c++) {
        float w = Wp[c * 256];
#pragma unroll
        for (int pp = 0; pp < 4; pp++) acc[pp] += xs[c * 4 + pp] * w;
    }
    float* out = half ? B : A;
    float bias = half ? 0.f : b1[col];         // fold b1 into A once
#pragma unroll
    for (int pp = 0; pp < 4; pp++)
        out[(bs * 16 + pg * 4 + pp) * 256 + col] = acc[pp] + bias;
}

// ---- W2/W3/W4 -> f16 fragment-contiguous layout: flat = frag*512 + lane*8 + e --
// frag = (L*16 + cg)*8 + kk ; col = cg*16 + (lane&15) ; k = kk*32 + (lane>>4)*8 + e
__global__ void prep_w(const float* __restrict__ W2, const float* __restrict__ W3,
                       const float* __restrict__ W4, _Float16* __restrict__ Wt) {
    int blk = blockIdx.x;                      // = frag index, 0..383
    int t   = threadIdx.x;                     // 0..511 = lane*8 + e
    int kk = blk & 7, cg = (blk >> 3) & 15, L = blk >> 7;
    int l = t >> 3, e = t & 7;
    int col = cg * 16 + (l & 15);
    int k   = kk * 32 + (l >> 4) * 8 + e;
    const float* W = (L == 0) ? W2 : (L == 1) ? W3 : W4;
    Wt[blk * 512 + t] = (_Float16)W[k * 256 + col];
}

// ---------------- the big fused kernel ------------------------------------------
// grid 1600 = (b,s1,s2) x 2 row-halves; 4 waves, each 128 rows x 64 cols
// single in-place LDS h buffer 128 x LDH (67.6 KB) -> 2 blocks/CU
__global__ __launch_bounds__(256, 2) void pairnet(
        const float* __restrict__ A, const float* __restrict__ B,
        const _Float16* __restrict__ Wt,
        const float* __restrict__ b2, const float* __restrict__ b3,
        const float* __restrict__ b4, float* __restrict__ pooled2) {
    __shared__ _Float16 hb[128 * LDH];         // 67.6 KB

    int blk  = blockIdx.x;
    int half = blk & 1;
    int bss  = blk >> 1;                       // (b*20+s1)*20+s2
    int s2   = bss % 20;
    int s1   = (bss / 20) % 20;
    int b    = bss / 400;
    int tid  = threadIdx.x;

    // ---- layer 1: h1 = relu(A[b,s2,p2] + B[b,s1,p1]), fp32 -> f16 into hb ----
    const float* Abase = A + (b * 20 + s2) * 16 * 256;
    const float* Bbase = B + ((b * 20 + s1) * 16 + half * 8) * 256;
#pragma unroll
    for (int it = 0; it < 32; it++) {
        int u = it * 256 + tid;            // float4-units, 0..8191
        int r = u >> 6;                    // row 0..127 (= p1loc*16 + p2)
        int c = (u & 63) * 4;              // col
        float4 av = *(const float4*)(Abase + (r & 15) * 256 + c);
        float4 bv = *(const float4*)(Bbase + (r >> 4) * 256 + c);
        f16x4 hv;
        hv[0] = (_Float16)fmaxf(av.x + bv.x, 0.f);
        hv[1] = (_Float16)fmaxf(av.y + bv.y, 0.f);
        hv[2] = (_Float16)fmaxf(av.z + bv.z, 0.f);
        hv[3] = (_Float16)fmaxf(av.w + bv.w, 0.f);
        *(f16x4*)(hb + r * LDH + c) = hv;
    }
    __syncthreads();

    int wid = tid >> 6, lane = tid & 63;
    int col0 = wid * 64;                   // wave owns 64 cols x all 128 rows
    int lr = lane & 15, lk = lane >> 4;

#pragma unroll
    for (int L = 0; L < 3; L++) {
        const float* bias = (L == 0) ? b2 : (L == 1) ? b3 : b4;
        // fragment-contiguous W base for this wave's 4 col-groups
        const _Float16* wb = Wt + (size_t)((L * 16 + wid * 4) * 8) * 512 + lane * 8;

        f32x4 acc[8][4];
#pragma unroll
        for (int m = 0; m < 8; m++)
#pragma unroll
            for (int n = 0; n < 4; n++) acc[m][n] = (f32x4){0.f, 0.f, 0.f, 0.f};

#pragma unroll
        for (int kk = 0; kk < 8; kk++) {
            f16x8 w[4];
#pragma unroll
            for (int n = 0; n < 4; n++)
                w[n] = *(const f16x8*)(wb + (n * 8 + kk) * 512);
            f16x8 a[8];
#pragma unroll
            for (int m = 0; m < 8; m++)
                a[m] = *(const f16x8*)(hb + (16 * m + lr) * LDH + kk * 32 + 8 * lk);
            // swapped operands -> transposed D: thread holds row 16m+lr,
            // cols col0+16n+4lk+{0..3}
#pragma unroll
            for (int m = 0; m < 8; m++)
#pragma unroll
                for (int n = 0; n < 4; n++)
                    acc[m][n] = __builtin_amdgcn_mfma_f32_16x16x32_f16(
                        w[n], a[m], acc[m][n], 0, 0, 0);
        }

        if (L < 2) {
            __syncthreads();               // all reads of hb complete
#pragma unroll
            for (int n = 0; n < 4; n++) {
                int cb = col0 + 16 * n + 4 * lk;
                float4 b4v = *(const float4*)(bias + cb);
#pragma unroll
                for (int m = 0; m < 8; m++) {
                    int row = 16 * m + lr;
                    f16x4 hv;
                    hv[0] = (_Float16)fmaxf(acc[m][n][0] + b4v.x, 0.f);
                    hv[1] = (_Float16)fmaxf(acc[m][n][1] + b4v.y, 0.f);
                    hv[2] = (_Float16)fmaxf(acc[m][n][2] + b4v.z, 0.f);
                    hv[3] = (_Float16)fmaxf(acc[m][n][3] + b4v.w, 0.f);
                    *(f16x4*)(hb + row * LDH + cb) = hv;
                }
            }
            __syncthreads();               // writes visible
        } else {
            // layer 4: bias+relu, pool over 128 rows (m in-thread, lr butterfly)
#pragma unroll
            for (int n = 0; n < 4; n++) {
                int cb = col0 + 16 * n + 4 * lk;
                float4 b4v = *(const float4*)(bias + cb);
                f32x4 s = (f32x4){0.f, 0.f, 0.f, 0.f};
#pragma unroll
                for (int m = 0; m < 8; m++) {
                    s[0] += fmaxf(acc[m][n][0] + b4v.x, 0.f);
                    s[1] += fmaxf(acc[m][n][1] + b4v.y, 0.f);
                    s[2] += fmaxf(acc[m][n][2] + b4v.z, 0.f);
                    s[3] += fmaxf(acc[m][n][3] + b4v.w, 0.f);
                }
#pragma unroll
                for (int mask = 1; mask <= 8; mask <<= 1) {
#pragma unroll
                    for (int c = 0; c < 4; c++) s[c] += __shfl_xor(s[c], mask);
                }
                if (lr == 0) {
                    float4 sv; sv.x = s[0]; sv.y = s[1]; sv.z = s[2]; sv.w = s[3];
                    *(float4*)(pooled2 + ((size_t)half * 800 + bss) * 256 + cb) = sv;
                }
            }
        }
    }
}

// ---------------- final MLP on pooled [800,256] (sums 2 half slabs) -------------
__global__ void final_mlp(const float* __restrict__ pooled2,
        const float* __restrict__ Wf1, const float* __restrict__ bf1,
        const float* __restrict__ Wf2, const float* __restrict__ bf2,
        const float* __restrict__ Wf3, const float* __restrict__ bf3,
        const float* __restrict__ Wf4, const float* __restrict__ bf4,
        float* __restrict__ out) {
    __shared__ float p[4][256], y[4][256], z[4][256], y3[4][29];
    int r0 = blockIdx.x * 4;
    int t  = threadIdx.x;
    for (int i = t; i < 1024; i += 256) {
        int r = i >> 8, c = i & 255;
        p[r][c] = pooled2[(size_t)(r0 + r) * 256 + c] +
                  pooled2[(size_t)(800 + r0 + r) * 256 + c];
    }
    __syncthreads();
    float acc[4];
#pragma unroll
    for (int r = 0; r < 4; r++) acc[r] = bf1[t];
    for (int k = 0; k < 256; k++) {
        float w = Wf1[k * 256 + t];
#pragma unroll
        for (int r = 0; r < 4; r++) acc[r] += p[r][k] * w;
    }
#pragma unroll
    for (int r = 0; r < 4; r++) y[r][t] = fmaxf(acc[r], 0.f);
    __syncthreads();
#pragma unroll
    for (int r = 0; r < 4; r++) acc[r] = bf2[t];
    for (int k = 0; k < 256; k++) {
        float w = Wf2[k * 256 + t];
#pragma unroll
        for (int r = 0; r < 4; r++) acc[r] += y[r][k] * w;
    }
#pragma unroll
    for (int r = 0; r < 4; r++) z[r][t] = fmaxf(acc[r], 0.f);
    __syncthreads();
    if (t < 116) {
        int r = t / 29, c = t % 29;
        float a = bf3[c];
        for (int k = 0; k < 256; k++) a += z[r][k] * Wf3[k * 29 + c];
        y3[r][c] = fmaxf(a, 0.f);
    }
    __syncthreads();
    if (t < 4) {
        float zz = bf4[0];
#pragma unroll
        for (int c = 0; c < 29; c++) zz += y3[t][c] * Wf4[c];
        out[r0 + t] = 1.f / (1.f + expf(-zz));
    }
}

extern "C" void kernel_launch(void* const* d_in, const int* in_sizes, int n_in,
                              void* d_out, int out_size, void* d_ws, size_t ws_size,
                              hipStream_t stream) {
    const float* x   = (const float*)d_in[0];
    const float* W1  = (const float*)d_in[1];
    const float* b1  = (const float*)d_in[2];
    const float* W2  = (const float*)d_in[3];
    const float* b2  = (const float*)d_in[4];
    const float* W3  = (const float*)d_in[5];
    const float* b3  = (const float*)d_in[6];
    const float* W4  = (const float*)d_in[7];
    const float* b4  = (const float*)d_in[8];
    const float* Wf1 = (const float*)d_in[9];
    const float* bf1 = (const float*)d_in[10];
    const float* Wf2 = (const float*)d_in[11];
    const float* bf2 = (const float*)d_in[12];
    const float* Wf3 = (const float*)d_in[13];
    const float* bf3 = (const float*)d_in[14];
    const float* Wf4 = (const float*)d_in[15];
    const float* bf4 = (const float*)d_in[16];

    float* A       = (float*)d_ws;                     // 640*256 f32
    float* B       = A + 640 * 256;                    // 640*256 f32
    float* pooled2 = B + 640 * 256;                    // 2*800*256 f32
    _Float16* Wt   = (_Float16*)(pooled2 + 2 * 800 * 256); // 384 frags * 512 f16

    prep_ab<<<160, 512, 0, stream>>>(x, W1, b1, A, B);
    prep_w<<<384, 512, 0, stream>>>(W2, W3, W4, Wt);
    pairnet<<<1600, 256, 0, stream>>>(A, B, Wt, b2, b3, b4, pooled2);
    final_mlp<<<200, 256, 0, stream>>>(pooled2, Wf1, bf1, Wf2, bf2, Wf3, bf3, Wf4, bf4,
                                       (float*)d_out);
}